// Round 2
// baseline (27.256 us; speedup 1.0000x reference)
//
#include <hip/hip_runtime.h>
#include <math.h>

// forecast (32,20,96,96) f32, truth (32,96,96) f32 -> scalar f32
#define M_ENS 20
#define HW2   4608            // 96*96/2 float2 per image
#define BHWf  294912.0f
#define NQ2   147456          // total float2 pixels = 32*96*96/2
#define BLOCK 256
#define NB    576             // NB*BLOCK == NQ2 exactly

__device__ __forceinline__ void block_reduce2(float& a, float& b) {
    __shared__ float s1[BLOCK];
    __shared__ float s2[BLOCK];
    int tid = threadIdx.x;
    __syncthreads();           // protect shared reuse across calls
    s1[tid] = a; s2[tid] = b;
    __syncthreads();
    for (int off = BLOCK / 2; off > 0; off >>= 1) {
        if (tid < off) { s1[tid] += s1[tid + off]; s2[tid] += s2[tid + off]; }
        __syncthreads();
    }
    a = s1[0]; b = s2[0];
}

__global__ void __launch_bounds__(BLOCK)
crps_fused_kernel(const float2* __restrict__ forecast,
                  const float2* __restrict__ truth,
                  float* __restrict__ partial,        // 2*NB floats in d_ws
                  unsigned int* __restrict__ counter, // zeroed each call
                  float* __restrict__ out) {
    int q  = blockIdx.x * BLOCK + threadIdx.x;        // exact cover, no tail
    int b  = q / HW2;
    int hw = q - b * HW2;
    const float2* fp = forecast + (size_t)b * (M_ENS * HW2) + hw;

    float2 v[M_ENS];
    #pragma unroll
    for (int e = 0; e < M_ENS; ++e) v[e] = fp[e * HW2];
    float2 yv = truth[q];

    float crps = 0.0f, pen = 0.0f;
    #pragma unroll
    for (int c = 0; c < 2; ++c) {
        float x[M_ENS];
        #pragma unroll
        for (int e = 0; e < M_ENS; ++e) x[e] = c ? v[e].y : v[e].x;
        float y = c ? yv.y : yv.x;

        float dxy = 0.0f, sum = 0.0f;
        #pragma unroll
        for (int e = 0; e < M_ENS; ++e) {
            dxy += fabsf(x[e] - y);
            sum += x[e];
        }

        float tri = 0.0f;                 // upper-triangle pair sum
        #pragma unroll
        for (int i = 0; i < M_ENS; ++i) {
            #pragma unroll
            for (int j = i + 1; j < M_ENS; ++j) {
                tri += fabsf(x[i] - x[j]);
            }
        }

        float mean = sum * (1.0f / M_ENS);
        float var = 0.0f;
        #pragma unroll
        for (int e = 0; e < M_ENS; ++e) {
            float d = x[e] - mean;
            var += d * d;
        }
        float stdv = sqrtf(var * (1.0f / (M_ENS - 1)));  // ddof=1
        float ks = 3.3f * stdv;

        #pragma unroll
        for (int e = 0; e < M_ENS; ++e) {
            float dev = fabsf(x[e] - mean);
            float p = dev - ks;
            pen += (p > 0.0f) ? p : 0.0f;
        }

        // dxx = 2*tri/m^2 (diag is zero); crps_px = dxy/m - 0.5*dxx
        crps += dxy * (1.0f / M_ENS) - tri * (1.0f / (M_ENS * M_ENS));
    }

    block_reduce2(crps, pen);

    __shared__ bool s_last;
    if (threadIdx.x == 0) {
        partial[blockIdx.x]      = crps;
        partial[NB + blockIdx.x] = pen;
        __threadfence();                       // publish partials (device scope)
        unsigned int old = atomicAdd(counter, 1u);
        s_last = (old == NB - 1);
    }
    __syncthreads();

    if (s_last) {                              // uniform across block
        __threadfence();                       // acquire: invalidate L1 before reads
        float c = 0.0f, p = 0.0f;
        for (int i = threadIdx.x; i < NB; i += BLOCK) {
            c += partial[i];
            p += partial[NB + i];
        }
        block_reduce2(c, p);
        if (threadIdx.x == 0) {
            out[0] = c * (1.0f / BHWf) + 0.02f * p * (1.0f / (BHWf * M_ENS));
        }
    }
}

extern "C" void kernel_launch(void* const* d_in, const int* in_sizes, int n_in,
                              void* d_out, int out_size, void* d_ws, size_t ws_size,
                              hipStream_t stream) {
    const float2* forecast = (const float2*)d_in[0];
    const float2* truth    = (const float2*)d_in[1];
    float* out = (float*)d_out;

    float* partial = (float*)d_ws;                            // 2*NB floats = 4608 B
    unsigned int* counter = (unsigned int*)((char*)d_ws + 2 * NB * sizeof(float));

    hipMemsetAsync(counter, 0, sizeof(unsigned int), stream); // capture-safe
    crps_fused_kernel<<<NB, BLOCK, 0, stream>>>(forecast, truth, partial, counter, out);
}

// Round 3
// 14.283 us; speedup vs baseline: 1.9083x; 1.9083x over previous
//
#include <hip/hip_runtime.h>
#include <math.h>

// forecast (32,20,96,96) f32, truth (32,96,96) f32 -> scalar f32
#define M_ENS 20
#define HW2   4608            // 96*96/2  (float2 per image)
#define BHWf  294912.0f
#define BLOCK 256
#define NB    576             // NB*BLOCK == 147456 float2 quanta, exact

__global__ void __launch_bounds__(BLOCK)
crps_partial_kernel(const float2* __restrict__ forecast,
                    const float2* __restrict__ truth,
                    float* __restrict__ partial) {
    int q  = blockIdx.x * BLOCK + threadIdx.x;   // exact cover, no tail
    int b  = q / HW2;
    int hw = q - b * HW2;
    const float2* fp = forecast + (size_t)b * (M_ENS * HW2) + hw;

    float2 v[M_ENS];
    #pragma unroll
    for (int e = 0; e < M_ENS; ++e) v[e] = fp[e * HW2];
    float2 yv = truth[q];

    float crps = 0.0f, pen = 0.0f;
    #pragma unroll
    for (int c = 0; c < 2; ++c) {
        float x[M_ENS];
        #pragma unroll
        for (int e = 0; e < M_ENS; ++e) x[e] = c ? v[e].y : v[e].x;
        float y = c ? yv.y : yv.x;

        float dxy = 0.0f, sum = 0.0f;
        #pragma unroll
        for (int e = 0; e < M_ENS; ++e) {
            dxy += fabsf(x[e] - y);
            sum += x[e];
        }

        float tri = 0.0f;                          // upper-triangle pair sum
        #pragma unroll
        for (int i = 0; i < M_ENS; ++i) {
            #pragma unroll
            for (int j = i + 1; j < M_ENS; ++j) {
                tri += fabsf(x[i] - x[j]);
            }
        }

        float mean = sum * (1.0f / M_ENS);
        float var = 0.0f;
        #pragma unroll
        for (int e = 0; e < M_ENS; ++e) {
            float d = x[e] - mean;
            var += d * d;
        }
        float stdv = sqrtf(var * (1.0f / (M_ENS - 1)));   // ddof=1
        float ks = 3.3f * stdv;

        #pragma unroll
        for (int e = 0; e < M_ENS; ++e) {
            float dev = fabsf(x[e] - mean);
            float p = dev - ks;
            pen += (p > 0.0f) ? p : 0.0f;
        }

        // dxx = 2*tri/m^2 (diag zero); crps_px = dxy/m - 0.5*dxx
        crps += dxy * (1.0f / M_ENS) - tri * (1.0f / (M_ENS * M_ENS));
    }

    // fold both sums with their final coefficients -> single accumulator
    float s = crps * (1.0f / BHWf) + pen * (0.02f / (BHWf * M_ENS));

    // wave64 shuffle reduce, then 4-entry LDS cross-wave reduce
    #pragma unroll
    for (int off = 32; off > 0; off >>= 1)
        s += __shfl_down(s, off, 64);

    __shared__ float sw[BLOCK / 64];
    int wave = threadIdx.x >> 6;
    int lane = threadIdx.x & 63;
    if (lane == 0) sw[wave] = s;
    __syncthreads();
    if (threadIdx.x == 0) {
        float t = sw[0];
        #pragma unroll
        for (int w = 1; w < BLOCK / 64; ++w) t += sw[w];
        partial[blockIdx.x] = t;
    }
}

__global__ void __launch_bounds__(64)
crps_final_kernel(const float* __restrict__ partial, float* __restrict__ out) {
    float s = 0.0f;
    #pragma unroll
    for (int i = 0; i < NB / 64; ++i)            // 9 strided loads, exact
        s += partial[i * 64 + threadIdx.x];
    #pragma unroll
    for (int off = 32; off > 0; off >>= 1)
        s += __shfl_down(s, off, 64);
    if (threadIdx.x == 0) out[0] = s;
}

extern "C" void kernel_launch(void* const* d_in, const int* in_sizes, int n_in,
                              void* d_out, int out_size, void* d_ws, size_t ws_size,
                              hipStream_t stream) {
    const float2* forecast = (const float2*)d_in[0];
    const float2* truth    = (const float2*)d_in[1];
    float* out = (float*)d_out;
    float* partial = (float*)d_ws;               // NB floats = 2304 B

    crps_partial_kernel<<<NB, BLOCK, 0, stream>>>(forecast, truth, partial);
    crps_final_kernel<<<1, 64, 0, stream>>>(partial, out);
}

// Round 4
// 11.593 us; speedup vs baseline: 2.3510x; 1.2320x over previous
//
#include <hip/hip_runtime.h>
#include <math.h>

// forecast (32,20,96,96) f32, truth (32,96,96) f32 -> scalar f32
#define M_ENS 20
#define HW    9216            // 96*96 pixels per image
#define BHWf  294912.0f
#define BLOCK 256
#define BPI   36              // blocks per image: 36*256 == 9216 exact
#define NB    1152            // 36*32 total blocks

__global__ void __launch_bounds__(BLOCK)
crps_partial_kernel(const float* __restrict__ forecast,
                    const float* __restrict__ truth,
                    float* __restrict__ partial) {
    int b  = blockIdx.y;                             // image index 0..31
    int hw = blockIdx.x * BLOCK + threadIdx.x;       // pixel in image, exact cover
    const float* fp = forecast + (size_t)b * (M_ENS * HW) + hw;

    float x[M_ENS];
    #pragma unroll
    for (int e = 0; e < M_ENS; ++e) x[e] = fp[e * HW];
    float y = truth[b * HW + hw];

    float dxy = 0.0f, sum = 0.0f;
    #pragma unroll
    for (int e = 0; e < M_ENS; ++e) {
        dxy += fabsf(x[e] - y);
        sum += x[e];
    }

    float tri = 0.0f;                                // upper-triangle pair sum
    #pragma unroll
    for (int i = 0; i < M_ENS; ++i) {
        #pragma unroll
        for (int j = i + 1; j < M_ENS; ++j) {
            tri += fabsf(x[i] - x[j]);
        }
    }

    float mean = sum * (1.0f / M_ENS);
    float var = 0.0f;
    #pragma unroll
    for (int e = 0; e < M_ENS; ++e) {
        float d = x[e] - mean;
        var += d * d;
    }
    float stdv = sqrtf(var * (1.0f / (M_ENS - 1)));  // ddof=1
    float ks = 3.3f * stdv;

    float pen = 0.0f;
    #pragma unroll
    for (int e = 0; e < M_ENS; ++e) {
        float dev = fabsf(x[e] - mean);
        float p = dev - ks;
        pen += (p > 0.0f) ? p : 0.0f;
    }

    // crps_px = dxy/m - tri/m^2 (diag zero); fold final coefficients now
    float s = (dxy * (1.0f / M_ENS) - tri * (1.0f / (M_ENS * M_ENS))) * (1.0f / BHWf)
            + pen * (0.02f / (BHWf * M_ENS));

    // wave64 shuffle reduce, then 4-entry LDS cross-wave reduce
    #pragma unroll
    for (int off = 32; off > 0; off >>= 1)
        s += __shfl_down(s, off, 64);

    __shared__ float sw[BLOCK / 64];
    int wave = threadIdx.x >> 6;
    int lane = threadIdx.x & 63;
    if (lane == 0) sw[wave] = s;
    __syncthreads();
    if (threadIdx.x == 0) {
        float t = sw[0] + sw[1] + sw[2] + sw[3];
        partial[blockIdx.y * BPI + blockIdx.x] = t;
    }
}

__global__ void __launch_bounds__(64)
crps_final_kernel(const float* __restrict__ partial, float* __restrict__ out) {
    float s = 0.0f;
    #pragma unroll
    for (int i = 0; i < NB / 64; ++i)                // 18 strided loads, exact
        s += partial[i * 64 + threadIdx.x];
    #pragma unroll
    for (int off = 32; off > 0; off >>= 1)
        s += __shfl_down(s, off, 64);
    if (threadIdx.x == 0) out[0] = s;
}

extern "C" void kernel_launch(void* const* d_in, const int* in_sizes, int n_in,
                              void* d_out, int out_size, void* d_ws, size_t ws_size,
                              hipStream_t stream) {
    const float* forecast = (const float*)d_in[0];
    const float* truth    = (const float*)d_in[1];
    float* out = (float*)d_out;
    float* partial = (float*)d_ws;                   // NB floats = 4608 B

    dim3 grid(BPI, 32);
    crps_partial_kernel<<<grid, BLOCK, 0, stream>>>(forecast, truth, partial);
    crps_final_kernel<<<1, 64, 0, stream>>>(partial, out);
}